// Round 5
// baseline (95.746 us; speedup 1.0000x reference)
//
#include <hip/hip_runtime.h>
#include <hip/hip_bf16.h>

// out[s,d] = (sum_{t in seg s} log1p(inten[t]) * emb[t,d] + W0*offset[d])
//            / (sum_{t in seg s} log1p(inten[t]) + W0)
// segment_ids sorted -> contiguous ranges. Two kernels:
//  1) boundary scan -> starts[B+1] in d_ws
//  2) ONE WAVE PER SEGMENT, block=64 (1 wave/WG -> ZERO WG-retire
//     slot-holding; 65536 independent WGs keep dynamic refill, R3 lesson).
//     16 waves/CU residency is enough: 16 x 2KB in flight >> 9KB BW-latency
//     product. 4 token-subgroups x 16 dim-quads, 8 tokens/iter main loop
//     (2 independent float4 nontemporal streams), butterfly reduce.

#define W0 0.69314718055994530942f  // log1p(1.0)

typedef float f32x4 __attribute__((ext_vector_type(4)));

__global__ void seg_bounds_kernel(const int* __restrict__ ids,
                                  int* __restrict__ starts,
                                  int T, int B) {
    int t = blockIdx.x * blockDim.x + threadIdx.x;
    if (t >= T) return;
    int cur  = ids[t];
    int prev = (t == 0) ? -1 : ids[t - 1];
    for (int s = prev + 1; s <= cur; ++s) starts[s] = t;
    if (t == T - 1) {
        for (int s = cur + 1; s <= B; ++s) starts[s] = T;
    }
}

__global__ void __launch_bounds__(64)
seg_embed_kernel(const float* __restrict__ emb,
                 const float* __restrict__ inten,
                 const int*   __restrict__ starts,
                 const float* __restrict__ offset_tok,
                 float* __restrict__ out,
                 int B) {
    const int seg = blockIdx.x;          // one wave == one WG == one segment
    if (seg >= B) return;
    const int lane = threadIdx.x & 63;
    const int tgrp = lane >> 4;          // token subgroup 0..3
    const int dq   = lane & 15;          // dim quad: dims [dq*4, dq*4+3]

    const int t0 = starts[seg];
    const int t1 = starts[seg + 1];

    f32x4 acc0 = {0.f, 0.f, 0.f, 0.f};
    f32x4 acc1 = {0.f, 0.f, 0.f, 0.f};
    float wsum0 = 0.f, wsum1 = 0.f;

    int t = t0;
    // main loop: 8 tokens per trip, two independent load streams
    for (; t + 8 <= t1; t += 8) {
        const int ta = t + tgrp;
        const int tb = t + 4 + tgrp;
        const float ia = inten[ta];
        const float ib = inten[tb];
        const f32x4 ea = __builtin_nontemporal_load(
            reinterpret_cast<const f32x4*>(emb + (size_t)ta * 64 + dq * 4));
        const f32x4 eb = __builtin_nontemporal_load(
            reinterpret_cast<const f32x4*>(emb + (size_t)tb * 64 + dq * 4));
        const float wa = __logf(1.0f + ia);
        const float wb = __logf(1.0f + ib);
        acc0[0] = fmaf(ea[0], wa, acc0[0]);
        acc0[1] = fmaf(ea[1], wa, acc0[1]);
        acc0[2] = fmaf(ea[2], wa, acc0[2]);
        acc0[3] = fmaf(ea[3], wa, acc0[3]);
        wsum0 += wa;
        acc1[0] = fmaf(eb[0], wb, acc1[0]);
        acc1[1] = fmaf(eb[1], wb, acc1[1]);
        acc1[2] = fmaf(eb[2], wb, acc1[2]);
        acc1[3] = fmaf(eb[3], wb, acc1[3]);
        wsum1 += wb;
    }
    // one full 4-token group
    if (t + 4 <= t1) {
        const int ta = t + tgrp;
        const float ia = inten[ta];
        const f32x4 ea = __builtin_nontemporal_load(
            reinterpret_cast<const f32x4*>(emb + (size_t)ta * 64 + dq * 4));
        const float wa = __logf(1.0f + ia);
        acc0[0] = fmaf(ea[0], wa, acc0[0]);
        acc0[1] = fmaf(ea[1], wa, acc0[1]);
        acc0[2] = fmaf(ea[2], wa, acc0[2]);
        acc0[3] = fmaf(ea[3], wa, acc0[3]);
        wsum0 += wa;
        t += 4;
    }
    // masked tail (< 4 tokens)
    if (t + tgrp < t1) {
        const int ta = t + tgrp;
        const float ia = inten[ta];
        const f32x4 ea = *reinterpret_cast<const f32x4*>(
            emb + (size_t)ta * 64 + dq * 4);
        const float wa = __logf(1.0f + ia);
        acc1[0] = fmaf(ea[0], wa, acc1[0]);
        acc1[1] = fmaf(ea[1], wa, acc1[1]);
        acc1[2] = fmaf(ea[2], wa, acc1[2]);
        acc1[3] = fmaf(ea[3], wa, acc1[3]);
        wsum1 += wa;
    }

    f32x4 acc;
    acc[0] = acc0[0] + acc1[0];
    acc[1] = acc0[1] + acc1[1];
    acc[2] = acc0[2] + acc1[2];
    acc[3] = acc0[3] + acc1[3];
    float wsum = wsum0 + wsum1;

    // butterfly reduce across the 4 token subgroups (bits 4,5 of lane)
    acc[0] += __shfl_xor(acc[0], 16); acc[1] += __shfl_xor(acc[1], 16);
    acc[2] += __shfl_xor(acc[2], 16); acc[3] += __shfl_xor(acc[3], 16);
    wsum   += __shfl_xor(wsum, 16);
    acc[0] += __shfl_xor(acc[0], 32); acc[1] += __shfl_xor(acc[1], 32);
    acc[2] += __shfl_xor(acc[2], 32); acc[3] += __shfl_xor(acc[3], 32);
    wsum   += __shfl_xor(wsum, 32);

    if (lane < 16) {
        const f32x4 off = *reinterpret_cast<const f32x4*>(offset_tok + dq * 4);
        const float inv = 1.0f / (wsum + W0);
        f32x4 r;
        r[0] = (acc[0] + W0 * off[0]) * inv;
        r[1] = (acc[1] + W0 * off[1]) * inv;
        r[2] = (acc[2] + W0 * off[2]) * inv;
        r[3] = (acc[3] + W0 * off[3]) * inv;
        __builtin_nontemporal_store(
            r, reinterpret_cast<f32x4*>(out + (size_t)seg * 64 + dq * 4));
    }
}

extern "C" void kernel_launch(void* const* d_in, const int* in_sizes, int n_in,
                              void* d_out, int out_size, void* d_ws, size_t ws_size,
                              hipStream_t stream) {
    const float* emb        = (const float*)d_in[0];
    const float* inten      = (const float*)d_in[1];
    const int*   ids        = (const int*)d_in[2];
    const float* offset_tok = (const float*)d_in[3];
    float*       out        = (float*)d_out;

    const int T = in_sizes[1];       // TOTAL_TOKENS
    const int B = out_size / 64;     // NUM_SEGMENTS (D = 64)

    int* starts = (int*)d_ws;        // B+1 ints

    {
        const int block = 256;
        const int grid  = (T + block - 1) / block;
        seg_bounds_kernel<<<grid, block, 0, stream>>>(ids, starts, T, B);
    }
    {
        // one wave per WG, one WG per segment
        seg_embed_kernel<<<B, 64, 0, stream>>>(emb, inten, starts,
                                               offset_tok, out, B);
    }
}

// Round 6
// 94.134 us; speedup vs baseline: 1.0171x; 1.0171x over previous
//
#include <hip/hip_runtime.h>
#include <hip/hip_bf16.h>

// out[s,d] = (sum_{t in seg s} log1p(inten[t]) * emb[t,d] + W0*offset[d])
//            / (sum_{t in seg s} log1p(inten[t]) + W0)
// segment_ids sorted -> contiguous ranges. Two kernels:
//  1) boundary scan -> starts[B+1] in d_ws
//  2) one wave per segment, block=128 (R4 best). 16 tokens/trip main loop:
//     4 independent float4 nontemporal streams = 4KB in flight per wave.
//     Epilogue: 8-group, 4-group, masked tail. Butterfly reduce, NT store.
//     t0/t1 scalarized via readfirstlane (wave-uniform loop bounds).

#define W0 0.69314718055994530942f  // log1p(1.0)

typedef float f32x4 __attribute__((ext_vector_type(4)));

__global__ void seg_bounds_kernel(const int* __restrict__ ids,
                                  int* __restrict__ starts,
                                  int T, int B) {
    int t = blockIdx.x * blockDim.x + threadIdx.x;
    if (t >= T) return;
    int cur  = ids[t];
    int prev = (t == 0) ? -1 : ids[t - 1];
    for (int s = prev + 1; s <= cur; ++s) starts[s] = t;
    if (t == T - 1) {
        for (int s = cur + 1; s <= B; ++s) starts[s] = T;
    }
}

__device__ __forceinline__ void accum4(const float* __restrict__ emb,
                                       const float* __restrict__ inten,
                                       int ta, int dq, f32x4& acc, float& ws) {
    const float ia = inten[ta];
    const f32x4 ea = __builtin_nontemporal_load(
        reinterpret_cast<const f32x4*>(emb + (size_t)ta * 64 + dq * 4));
    const float wa = __logf(1.0f + ia);
    acc[0] = fmaf(ea[0], wa, acc[0]);
    acc[1] = fmaf(ea[1], wa, acc[1]);
    acc[2] = fmaf(ea[2], wa, acc[2]);
    acc[3] = fmaf(ea[3], wa, acc[3]);
    ws += wa;
}

__global__ void __launch_bounds__(128)
seg_embed_kernel(const float* __restrict__ emb,
                 const float* __restrict__ inten,
                 const int*   __restrict__ starts,
                 const float* __restrict__ offset_tok,
                 float* __restrict__ out,
                 int B) {
    const int seg = (blockIdx.x * blockDim.x + threadIdx.x) >> 6;
    if (seg >= B) return;
    const int lane = threadIdx.x & 63;
    const int tgrp = lane >> 4;          // token subgroup 0..3
    const int dq   = lane & 15;          // dim quad: dims [dq*4, dq*4+3]

    const int t0 = __builtin_amdgcn_readfirstlane(starts[seg]);
    const int t1 = __builtin_amdgcn_readfirstlane(starts[seg + 1]);

    f32x4 acc0 = {0.f, 0.f, 0.f, 0.f};
    f32x4 acc1 = {0.f, 0.f, 0.f, 0.f};
    f32x4 acc2 = {0.f, 0.f, 0.f, 0.f};
    f32x4 acc3 = {0.f, 0.f, 0.f, 0.f};
    float ws0 = 0.f, ws1 = 0.f, ws2 = 0.f, ws3 = 0.f;

    int t = t0;
    // main loop: 16 tokens per trip, four independent load streams
    for (; t + 16 <= t1; t += 16) {
        const int base = t + tgrp;
        const int taa = base;
        const int tab = base + 4;
        const int tac = base + 8;
        const int tad = base + 12;
        const float ia = inten[taa];
        const float ib = inten[tab];
        const float ic = inten[tac];
        const float id = inten[tad];
        const f32x4 ea = __builtin_nontemporal_load(
            reinterpret_cast<const f32x4*>(emb + (size_t)taa * 64 + dq * 4));
        const f32x4 eb = __builtin_nontemporal_load(
            reinterpret_cast<const f32x4*>(emb + (size_t)tab * 64 + dq * 4));
        const f32x4 ec = __builtin_nontemporal_load(
            reinterpret_cast<const f32x4*>(emb + (size_t)tac * 64 + dq * 4));
        const f32x4 ed = __builtin_nontemporal_load(
            reinterpret_cast<const f32x4*>(emb + (size_t)tad * 64 + dq * 4));
        const float wa = __logf(1.0f + ia);
        const float wb = __logf(1.0f + ib);
        const float wc = __logf(1.0f + ic);
        const float wd = __logf(1.0f + id);
        acc0[0] = fmaf(ea[0], wa, acc0[0]);
        acc0[1] = fmaf(ea[1], wa, acc0[1]);
        acc0[2] = fmaf(ea[2], wa, acc0[2]);
        acc0[3] = fmaf(ea[3], wa, acc0[3]);
        ws0 += wa;
        acc1[0] = fmaf(eb[0], wb, acc1[0]);
        acc1[1] = fmaf(eb[1], wb, acc1[1]);
        acc1[2] = fmaf(eb[2], wb, acc1[2]);
        acc1[3] = fmaf(eb[3], wb, acc1[3]);
        ws1 += wb;
        acc2[0] = fmaf(ec[0], wc, acc2[0]);
        acc2[1] = fmaf(ec[1], wc, acc2[1]);
        acc2[2] = fmaf(ec[2], wc, acc2[2]);
        acc2[3] = fmaf(ec[3], wc, acc2[3]);
        ws2 += wc;
        acc3[0] = fmaf(ed[0], wd, acc3[0]);
        acc3[1] = fmaf(ed[1], wd, acc3[1]);
        acc3[2] = fmaf(ed[2], wd, acc3[2]);
        acc3[3] = fmaf(ed[3], wd, acc3[3]);
        ws3 += wd;
    }
    // 8-token group
    if (t + 8 <= t1) {
        accum4(emb, inten, t + tgrp,     dq, acc0, ws0);
        accum4(emb, inten, t + 4 + tgrp, dq, acc1, ws1);
        t += 8;
    }
    // 4-token group
    if (t + 4 <= t1) {
        accum4(emb, inten, t + tgrp, dq, acc2, ws2);
        t += 4;
    }
    // masked tail (< 4 tokens)
    if (t + tgrp < t1) {
        const int ta = t + tgrp;
        const float ia = inten[ta];
        const f32x4 ea = *reinterpret_cast<const f32x4*>(
            emb + (size_t)ta * 64 + dq * 4);
        const float wa = __logf(1.0f + ia);
        acc3[0] = fmaf(ea[0], wa, acc3[0]);
        acc3[1] = fmaf(ea[1], wa, acc3[1]);
        acc3[2] = fmaf(ea[2], wa, acc3[2]);
        acc3[3] = fmaf(ea[3], wa, acc3[3]);
        ws3 += ia == ia ? wa : 0.f;  // keep dependence shape; wa always valid
    }

    f32x4 acc;
    acc[0] = (acc0[0] + acc1[0]) + (acc2[0] + acc3[0]);
    acc[1] = (acc0[1] + acc1[1]) + (acc2[1] + acc3[1]);
    acc[2] = (acc0[2] + acc1[2]) + (acc2[2] + acc3[2]);
    acc[3] = (acc0[3] + acc1[3]) + (acc2[3] + acc3[3]);
    float wsum = (ws0 + ws1) + (ws2 + ws3);

    // butterfly reduce across the 4 token subgroups (bits 4,5 of lane)
    acc[0] += __shfl_xor(acc[0], 16); acc[1] += __shfl_xor(acc[1], 16);
    acc[2] += __shfl_xor(acc[2], 16); acc[3] += __shfl_xor(acc[3], 16);
    wsum   += __shfl_xor(wsum, 16);
    acc[0] += __shfl_xor(acc[0], 32); acc[1] += __shfl_xor(acc[1], 32);
    acc[2] += __shfl_xor(acc[2], 32); acc[3] += __shfl_xor(acc[3], 32);
    wsum   += __shfl_xor(wsum, 32);

    if (lane < 16) {
        const f32x4 off = *reinterpret_cast<const f32x4*>(offset_tok + dq * 4);
        const float inv = 1.0f / (wsum + W0);
        f32x4 r;
        r[0] = (acc[0] + W0 * off[0]) * inv;
        r[1] = (acc[1] + W0 * off[1]) * inv;
        r[2] = (acc[2] + W0 * off[2]) * inv;
        r[3] = (acc[3] + W0 * off[3]) * inv;
        __builtin_nontemporal_store(
            r, reinterpret_cast<f32x4*>(out + (size_t)seg * 64 + dq * 4));
    }
}

extern "C" void kernel_launch(void* const* d_in, const int* in_sizes, int n_in,
                              void* d_out, int out_size, void* d_ws, size_t ws_size,
                              hipStream_t stream) {
    const float* emb        = (const float*)d_in[0];
    const float* inten      = (const float*)d_in[1];
    const int*   ids        = (const int*)d_in[2];
    const float* offset_tok = (const float*)d_in[3];
    float*       out        = (float*)d_out;

    const int T = in_sizes[1];       // TOTAL_TOKENS
    const int B = out_size / 64;     // NUM_SEGMENTS (D = 64)

    int* starts = (int*)d_ws;        // B+1 ints

    {
        const int block = 256;
        const int grid  = (T + block - 1) / block;
        seg_bounds_kernel<<<grid, block, 0, stream>>>(ids, starts, T, B);
    }
    {
        const int block = 128;                       // 2 waves/block (R4 best)
        const int grid  = (B * 64 + block - 1) / block;
        seg_embed_kernel<<<grid, block, 0, stream>>>(emb, inten, starts,
                                                     offset_tok, out, B);
    }
}